// Round 4
// baseline (7397.811 us; speedup 1.0000x reference)
//
#include <hip/hip_runtime.h>
#include <hip/hip_bf16.h>
#include <math.h>

// ---------------------------------------------------------------------------
// DecoderTARDIS forward, fp32, persistent kernel v2.
// Round-3 lesson (rocprof): FETCH_SIZE 1.1GB/dispatch = Wcat re-streamed from
// HBM every step (5.4MB > 4MB/XCD L2 -> thrash). Fix: Wcat LDS-resident,
// 8 cols/block loaded once. val/valW/u2w moved into phase A (idle blocks).
// ---------------------------------------------------------------------------

static constexpr int LL    = 32;
static constexpr int BB    = 128;
static constexpr int ID    = 512;
static constexpr int HD    = 1024;
static constexpr int NS    = 512;
static constexpr int AA    = 128;
static constexpr int CCd   = 128;
static constexpr int AC    = 256;
static constexpr int WC    = 1344;
static constexpr int COL_W0  = 1024;
static constexpr int COL_G0  = 1280;
static constexpr int COL_AB0 = 1283;
static constexpr int COL_TAU = 1285;
static constexpr int GRID_P  = 256;

// ------------------------------ threefry -----------------------------------
__device__ __forceinline__ uint32_t rotl32(uint32_t x, uint32_t r) {
  return (x << r) | (x >> (32u - r));
}

__device__ __forceinline__ void threefry2x32(uint32_t k0, uint32_t k1,
                                             uint32_t x0, uint32_t x1,
                                             uint32_t& o0, uint32_t& o1) {
  uint32_t ks0 = k0, ks1 = k1, ks2 = 0x1BD11BDAu ^ k0 ^ k1;
  x0 += ks0; x1 += ks1;
#define TFR(r) { x0 += x1; x1 = rotl32(x1, r); x1 ^= x0; }
  TFR(13u) TFR(15u) TFR(26u) TFR(6u)   x0 += ks1; x1 += ks2 + 1u;
  TFR(17u) TFR(29u) TFR(16u) TFR(24u)  x0 += ks2; x1 += ks0 + 2u;
  TFR(13u) TFR(15u) TFR(26u) TFR(6u)   x0 += ks0; x1 += ks1 + 3u;
  TFR(17u) TFR(29u) TFR(16u) TFR(24u)  x0 += ks1; x1 += ks2 + 4u;
  TFR(13u) TFR(15u) TFR(26u) TFR(6u)   x0 += ks2; x1 += ks0 + 5u;
#undef TFR
  o0 = x0; o1 = x1;
}

__device__ __forceinline__ float bits_to_gumbel(uint32_t bits) {
  uint32_t v = (bits >> 9) | 0x3F800000u;
  float f = __uint_as_float(v) - 1.0f;
  if (f <= 0.0f) f = 1.17549435e-38f;
  return -logf(-logf(f));
}

__device__ __forceinline__ float fast_tanh(float x) {
  float e = __expf(2.0f * x);      // native v_exp path; saturates correctly
  return 1.0f - 2.0f / (e + 1.0f);
}

// ------------------------------ grid barrier -------------------------------
__device__ __forceinline__ void grid_barrier(unsigned int* ctr, unsigned int& target) {
  __syncthreads();
  if (threadIdx.x == 0) {
    target += GRID_P;
    __hip_atomic_fetch_add(ctr, 1u, __ATOMIC_RELEASE, __HIP_MEMORY_SCOPE_AGENT);
    while (__hip_atomic_load(ctr, __ATOMIC_RELAXED, __HIP_MEMORY_SCOPE_AGENT) < target) {
      __builtin_amdgcn_s_sleep(1);
    }
    (void)__hip_atomic_load(ctr, __ATOMIC_ACQUIRE, __HIP_MEMORY_SCOPE_AGENT);
  }
  __syncthreads();
}

// ------------------------------ prologue -----------------------------------
__global__ void pack_wcat(const float* __restrict__ Wh2c, const float* __restrict__ Wh2w,
                          const float* __restrict__ Wh2g, const float* __restrict__ Wh2ab,
                          const float* __restrict__ Wh2tau, float* __restrict__ Wcat) {
  int idx = blockIdx.x * blockDim.x + threadIdx.x;
  if (idx >= HD * WC) return;
  int k = idx / WC, c = idx % WC;
  float v = 0.0f;
  if (c < 1024)       v = Wh2c[(size_t)k * HD + c];
  else if (c < 1280)  v = Wh2w[(size_t)k * AC + (c - 1024)];
  else if (c < 1283)  v = Wh2g[k * 3 + (c - 1280)];
  else if (c < 1285)  v = Wh2ab[k * 2 + (c - 1283)];
  else if (c == 1285) v = Wh2tau[k];
  Wcat[idx] = v;
}

__global__ void pack_wicat(const float* __restrict__ Wi2c, const float* __restrict__ Wi2w,
                           const float* __restrict__ Wi2g, const float* __restrict__ Wi2ab,
                           float* __restrict__ Wicat) {
  int idx = blockIdx.x * blockDim.x + threadIdx.x;
  if (idx >= ID * WC) return;
  int k = idx / WC, c = idx % WC;
  float v = 0.0f;
  if (c < 1024)      v = Wi2c[(size_t)k * HD + c];
  else if (c < 1280) v = Wi2w[(size_t)k * AC + (c - 1024)];
  else if (c < 1283) v = Wi2g[k * 3 + (c - 1280)];
  else if (c < 1285) v = Wi2ab[k * 2 + (c - 1283)];
  Wicat[idx] = v;
}

__global__ void addrw_kernel(const float* __restrict__ mem_bias,
                             const float* __restrict__ Wm2w,
                             float* __restrict__ addrW, float* __restrict__ addrWT) {
  int idx = blockIdx.x * blockDim.x + threadIdx.x;
  if (idx >= NS * AC) return;
  int n = idx / AC, m = idx % AC;
  float acc = 0.0f;
  for (int k = 0; k < AA; k++) acc += mem_bias[(size_t)n * AC + k] * Wm2w[(size_t)k * AC + m];
  addrW[(size_t)n * AC + m] = acc;
  addrWT[(size_t)m * NS + n] = acc;
}

__global__ void init_kernel(const float* __restrict__ hid, float* __restrict__ h,
                            float* __restrict__ cc, float* __restrict__ w_sum,
                            int* __restrict__ lastWriter, float* __restrict__ u2w,
                            unsigned int* __restrict__ bar_ctr) {
  int idx = blockIdx.x * blockDim.x + threadIdx.x;
  if (idx < BB * HD) { h[idx] = hid[idx]; cc[idx] = 0.0f; }
  if (idx < BB * NS) { w_sum[idx] = 0.0f; lastWriter[idx] = -1; }
  if (idx < BB * AC) { u2w[idx] = 0.0f; }
  if (idx == 0) bar_ctr[0] = 0u;
}

// -------- big fp32 GEMM (icat = inp @ Wicat), 128x64 tile, 8x4/thread ------
__global__ __launch_bounds__(256) void gemm_big(const float* __restrict__ A,
                                                const float* __restrict__ W,
                                                float* __restrict__ C) {
  __shared__ float sA[32][132];   // [kk][r], pad to avoid conflicts
  __shared__ float sB[32][68];    // [kk][c]
  const int tx = threadIdx.x & 15, ty = threadIdx.x >> 4;
  const int m0 = blockIdx.x * 128, n0 = blockIdx.y * 64;
  float acc[8][4] = {};
  for (int k0 = 0; k0 < ID; k0 += 32) {
    for (int i = threadIdx.x; i < 128 * 32; i += 256) {
      int r = i >> 5, kk = i & 31;
      sA[kk][r] = A[(size_t)(m0 + r) * ID + k0 + kk];
    }
    for (int i = threadIdx.x; i < 32 * 64; i += 256) {
      int kk = i >> 6, c = i & 63;
      sB[kk][c] = W[(size_t)(k0 + kk) * WC + n0 + c];
    }
    __syncthreads();
#pragma unroll
    for (int kk = 0; kk < 32; ++kk) {
      float4 a0 = *(const float4*)&sA[kk][ty * 8];
      float4 a1 = *(const float4*)&sA[kk][ty * 8 + 4];
      float4 b0 = *(const float4*)&sB[kk][tx * 4];
      float ar[8] = {a0.x, a0.y, a0.z, a0.w, a1.x, a1.y, a1.z, a1.w};
      float br[4] = {b0.x, b0.y, b0.z, b0.w};
#pragma unroll
      for (int i2 = 0; i2 < 8; ++i2)
#pragma unroll
        for (int j2 = 0; j2 < 4; ++j2)
          acc[i2][j2] = fmaf(ar[i2], br[j2], acc[i2][j2]);
    }
    __syncthreads();
  }
#pragma unroll
  for (int i2 = 0; i2 < 8; ++i2) {
    float4 st = make_float4(acc[i2][0], acc[i2][1], acc[i2][2], acc[i2][3]);
    *(float4*)&C[(size_t)(m0 + ty * 8 + i2) * WC + n0 + tx * 4] = st;
  }
}

// ------------------------------ persistent kernel --------------------------
struct SMemL { float bias[AC]; float att[AC]; float zl[256]; float avv[256]; int aii[256]; };
struct SMemV { float hls[HD]; float vhalf[512]; float vs[CCd]; float zn[512]; };
struct SMemS { float rs[AC]; };
union SMemU { SMemL l; SMemV v; SMemS s; };

__global__ __launch_bounds__(512) void persist_kernel(
    const float* __restrict__ icat, const float* __restrict__ Wcat,
    const float* __restrict__ addrW, const float* __restrict__ addrWT,
    const float* __restrict__ atten, const float* __restrict__ mem_bias,
    const float* __restrict__ Wr2g, const float* __restrict__ Wr2ab,
    const float* __restrict__ Wr2c, const float* __restrict__ Wh2m,
    const float* __restrict__ Wm2w, const float* __restrict__ Wu2w,
    const float* __restrict__ b_h2tau,
    float* hbuf, float* ccbuf, float* w_sum, float* u2w,
    float* valHist, float* valWHist, int* lastWriter, int* writePos,
    float* hcat, float* zbuf, float* gmaxv, int* gmaxi,
    unsigned int* bar_ctr, float* out) {
  const int blk = blockIdx.x, tid = threadIdx.x;
  const int lane = tid & 63, wv = tid >> 6;
  __shared__ float smWt[8][1028];   // persistent Wcat slice (A-blocks), 32.9KB
  __shared__ SMemU sm;
  __shared__ float red[8], gdot[5], s_fio[3], s_ab[2], s_tau, s_zmax;
  __shared__ int s_ns;
  unsigned int target = 0;

  uint32_t k1a, k1b, k2a, k2b;
  threefry2x32(0u, 42u, 0u, 0u, k1a, k1b);
  threefry2x32(0u, 42u, 0u, 1u, k2a, k2b);

  // one-time: load this block's 8 Wcat columns into LDS (transposed, padded)
  const int n0 = blk * 8;
  if (blk < 168) {
    for (int i = tid; i < 8192; i += 512) {
      int k = i >> 3, c = i & 7;
      smWt[c][k] = Wcat[(size_t)k * WC + n0 + c];
    }
  }
  __syncthreads();

  for (int t = 0; t < LL; ++t) {
    // ======== phase A: hcat GEMM (blocks 0..167) | val/valW/u2w (168..255) ==
    if (blk < 168) {
      const int c = tid & 7, rp = tid >> 3;
      const float4* h0 = (const float4*)(hbuf + (size_t)(2 * rp) * HD);
      const float4* h1 = (const float4*)(hbuf + (size_t)(2 * rp + 1) * HD);
      const float4* wt = (const float4*)&smWt[c][0];
      float acc0 = 0.0f, acc1 = 0.0f;
#pragma unroll 8
      for (int k4 = 0; k4 < 256; ++k4) {
        float4 a0 = h0[k4], a1 = h1[k4], w = wt[k4];
        acc0 = fmaf(a0.x, w.x, fmaf(a0.y, w.y, fmaf(a0.z, w.z, fmaf(a0.w, w.w, acc0))));
        acc1 = fmaf(a1.x, w.x, fmaf(a1.y, w.y, fmaf(a1.z, w.z, fmaf(a1.w, w.w, acc1))));
      }
      hcat[(size_t)(2 * rp) * WC + n0 + c] = acc0;
      hcat[(size_t)(2 * rp + 1) * WC + n0 + c] = acc1;
    } else {
      const int i = blk - 168;
      for (int rep = 0; rep < 2; ++rep) {
        const int b = (rep == 0) ? i : 88 + i;
        if (b >= BB) break;
        if (t > 0) {
          // val(t-1) = h(t-1) @ Wh2m
          for (int k = tid; k < HD; k += 512) sm.v.hls[k] = hbuf[(size_t)b * HD + k];
          __syncthreads();
          {
            int c = tid & 127, q = tid >> 7;
            const float* wp = Wh2m + c;
            float acc = 0.0f;
            int kb = q * 256;
#pragma unroll 4
            for (int k = kb; k < kb + 256; ++k) acc = fmaf(sm.v.hls[k], wp[(size_t)k * CCd], acc);
            sm.v.vhalf[tid] = acc;
          }
          __syncthreads();
          if (tid < CCd) {
            float val = sm.v.vhalf[tid] + sm.v.vhalf[tid + 128] + sm.v.vhalf[tid + 256] + sm.v.vhalf[tid + 384];
            sm.v.vs[tid] = val;
            valHist[((size_t)b * LL + (t - 1)) * CCd + tid] = val;
          }
          __syncthreads();
          {
            int m = tid & 255, h2 = tid >> 8;
            float acc = 0.0f;
            int cb = h2 * 64;
#pragma unroll 4
            for (int cix = cb; cix < cb + 64; ++cix)
              acc = fmaf(sm.v.vs[cix], Wm2w[(size_t)(AA + cix) * AC + m], acc);
            sm.v.zn[tid] = acc;
          }
          __syncthreads();
          if (tid < AC) valWHist[((size_t)b * LL + (t - 1)) * AC + tid] = sm.v.zn[tid] + sm.v.zn[tid + 256];
          __syncthreads();
        }
        // u2w(t) = layernorm(w_sum) @ Wu2w
        {
          float v = w_sum[(size_t)b * NS + tid];
          float ssum = v;
          for (int off = 32; off; off >>= 1) ssum += __shfl_down(ssum, off, 64);
          if (lane == 0) red[wv] = ssum;
          __syncthreads();
          float mu = (red[0] + red[1] + red[2] + red[3] + red[4] + red[5] + red[6] + red[7]) / (float)NS;
          __syncthreads();
          float d = (v - mu) * (v - mu);
          for (int off = 32; off; off >>= 1) d += __shfl_down(d, off, 64);
          if (lane == 0) red[wv] = d;
          __syncthreads();
          float var = (red[0] + red[1] + red[2] + red[3] + red[4] + red[5] + red[6] + red[7]) / (float)NS;
          float rsq = rsqrtf(var + 1e-5f);
          sm.v.zn[tid] = (v - mu) * rsq;
          __syncthreads();
          {
            int m = tid & 255, h2 = tid >> 8;
            float acc = 0.0f;
            int kb2 = h2 * 256;
#pragma unroll 4
            for (int k = kb2; k < kb2 + 256; ++k) acc = fmaf(sm.v.zn[k], Wu2w[(size_t)k * AC + m], acc);
            sm.v.vhalf[tid] = acc;
          }
          __syncthreads();
          if (tid < AC) u2w[(size_t)b * AC + tid] = sm.v.vhalf[tid] + sm.v.vhalf[tid + 256];
          __syncthreads();
        }
      }
    }
    grid_barrier(bar_ctr, target);

    // ======== phase L: logits + gumbel + half-argmax (all 256 blocks) ======
    {
      const int b = blk >> 1, half = blk & 1, nbase = half * 256;
      if (tid < AC) {
        sm.l.bias[tid] = hcat[(size_t)b * WC + COL_W0 + tid] +
                         icat[(size_t)(t * BB + b) * WC + COL_W0 + tid] +
                         u2w[(size_t)b * AC + tid];
        sm.l.att[tid] = atten[tid];
      }
      __syncthreads();
      {
        const int nn = tid >> 1, kh = (tid & 1) * 128;
        const int n = nbase + nn;
        float p = 0.0f;
        const float* awt = addrWT + n;
#pragma unroll 8
        for (int k = kh; k < kh + 128; ++k)
          p = fmaf(fast_tanh(sm.l.bias[k] + awt[(size_t)k * NS]), sm.l.att[k], p);
        p += __shfl_xor(p, 1, 64);
        if ((tid & 1) == 0) sm.l.zl[nn] = p;
      }
      __syncthreads();
      for (int j = wv; j < t; j += 8) {
        int n2 = writePos[b * LL + j];
        if (n2 >= nbase && n2 < nbase + 256) {
          int s = lastWriter[b * NS + n2];
          const float* dw = valWHist + ((size_t)b * LL + s) * AC;
          const float* aw = addrW + (size_t)n2 * AC;
          float q = 0.0f;
          for (int k = lane; k < AC; k += 64)
            q = fmaf(fast_tanh(sm.l.bias[k] + aw[k] + dw[k]), sm.l.att[k], q);
          for (int off = 32; off; off >>= 1) q += __shfl_down(q, off, 64);
          if (lane == 0) sm.l.zl[n2 - nbase] = q;
        }
      }
      __syncthreads();
      if (tid < 256) {
        uint32_t gi = (uint32_t)((t * BB + b) * NS + nbase + tid);
        uint32_t o0, o1; threefry2x32(k1a, k1b, 0u, gi, o0, o1);
        float zb = sm.l.zl[tid] + bits_to_gumbel(o0 ^ o1);
        zbuf[(size_t)b * NS + nbase + tid] = zb;
        sm.l.avv[tid] = zb; sm.l.aii[tid] = nbase + tid;
      }
      __syncthreads();
      for (int off = 128; off; off >>= 1) {
        if (tid < off) {
          float c2 = sm.l.avv[tid + off]; int i2 = sm.l.aii[tid + off];
          if (c2 > sm.l.avv[tid] || (c2 == sm.l.avv[tid] && i2 < sm.l.aii[tid])) {
            sm.l.avv[tid] = c2; sm.l.aii[tid] = i2;
          }
        }
        __syncthreads();
      }
      if (tid == 0) { gmaxv[b * 2 + half] = sm.l.avv[0]; gmaxi[b * 2 + half] = sm.l.aii[0]; }
    }
    grid_barrier(bar_ctr, target);

    // ======== phase S: select / gates / LSTM update (blocks 0..127) ========
    if (blk < BB) {
      const int b = blk;
      const float* icrow = icat + (size_t)(t * BB + b) * WC;
      if (tid == 0) {
        float v0 = gmaxv[2 * b], v1 = gmaxv[2 * b + 1];
        int   i0 = gmaxi[2 * b], i1 = gmaxi[2 * b + 1];
        if (v1 > v0 || (v1 == v0 && i1 < i0)) { s_zmax = v1; s_ns = i1; }
        else { s_zmax = v0; s_ns = i0; }
        float x = hcat[(size_t)b * WC + COL_TAU] + b_h2tau[0];
        s_tau = fmaxf(x, 0.0f) + log1pf(expf(-fabsf(x))) + 1.0f;
      }
      __syncthreads();
      const float tau = s_tau, zmax = s_zmax; const int ns = s_ns;
      {
        float e = expf((zbuf[(size_t)b * NS + tid] - zmax) / tau);
        for (int off = 32; off; off >>= 1) e += __shfl_down(e, off, 64);
        if (lane == 0) red[wv] = e;
      }
      __syncthreads();
      const float D = red[0] + red[1] + red[2] + red[3] + red[4] + red[5] + red[6] + red[7];
      const float ystar = 1.0f / D;
      const float ws = (1.0f - ystar) + ystar;
      if (tid < AC) {
        int sW_ = lastWriter[b * NS + ns];
        float mv = (tid < AA) ? mem_bias[(size_t)ns * AC + tid]
                 : ((sW_ >= 0) ? valHist[((size_t)b * LL + sW_) * CCd + (tid - AA)] : 0.0f);
        sm.s.rs[tid] = ws * mv;
      }
      __syncthreads();
      if (tid == 0) {  // bookkeeping AFTER r-gather read lastWriter
        int pos = (t * LL < NS) ? (t * LL) : ns;
        writePos[b * LL + t] = pos;
        lastWriter[b * NS + pos] = t;
        w_sum[(size_t)b * NS + ns] += ws;
      }
      if (tid < 160) {
        int j = tid >> 5, l = tid & 31;
        float p = 0.0f;
        if (j < 3) { for (int k = l; k < AC; k += 32) p += sm.s.rs[k] * Wr2g[k * 3 + j]; }
        else { int jj = j - 3; for (int k = l; k < AC; k += 32) p += sm.s.rs[k] * Wr2ab[k * 2 + jj]; }
        for (int off = 16; off; off >>= 1) p += __shfl_down(p, off, 32);
        if (l == 0) gdot[j] = p;
      }
      __syncthreads();
      if (tid < 3) {
        float x = hcat[(size_t)b * WC + COL_G0 + tid] + icrow[COL_G0 + tid] + gdot[tid];
        s_fio[tid] = 1.0f / (1.0f + expf(-x));
      } else if (tid < 5) {
        int j = tid - 3;
        float x = hcat[(size_t)b * WC + COL_AB0 + j] + icrow[COL_AB0 + j] + gdot[tid];
        uint32_t i1 = (uint32_t)(((t * BB + b) * 2 + j) * 2);
        uint32_t o0, o1;
        threefry2x32(k2a, k2b, 0u, i1, o0, o1);     float g1 = bits_to_gumbel(o0 ^ o1);
        threefry2x32(k2a, k2b, 0u, i1 + 1, o0, o1); float g2 = bits_to_gumbel(o0 ^ o1);
        s_ab[j] = (x + g1 - g2) > 0.0f ? 1.0f : 0.0f;
      }
      __syncthreads();
      const float fg = s_fio[0], ig = s_fio[1], og = s_fio[2];
      const float alpha = s_ab[0], beta = s_ab[1];
      const int c0 = tid * 2;
      {
        float r0 = 0.0f, r1 = 0.0f;
#pragma unroll 4
        for (int k = 0; k < AC; ++k) {
          float rk = sm.s.rs[k];
          float2 w2 = *(const float2*)&Wr2c[(size_t)k * HD + c0];
          r0 = fmaf(rk, w2.x, r0); r1 = fmaf(rk, w2.y, r1);
        }
        float2 hc2 = *(const float2*)&hcat[(size_t)b * WC + c0];
        float2 ic2 = *(const float2*)&icrow[c0];
        float2 cc2 = *(const float2*)&ccbuf[(size_t)b * HD + c0];
        float a0 = beta * hc2.x + ic2.x + alpha * r0;
        float a1 = beta * hc2.y + ic2.y + alpha * r1;
        float cn0 = fg * cc2.x + ig * tanhf(a0);
        float cn1 = fg * cc2.y + ig * tanhf(a1);
        float hn0 = og * tanhf(cn0), hn1 = og * tanhf(cn1);
        *(float2*)&ccbuf[(size_t)b * HD + c0] = make_float2(cn0, cn1);
        *(float2*)&hbuf[(size_t)b * HD + c0] = make_float2(hn0, hn1);
        *(float2*)&out[((size_t)t * BB + b) * HD + c0] = make_float2(hn0, hn1);
      }
    }
    grid_barrier(bar_ctr, target);
  }
}

// ------------------------------ host ---------------------------------------
extern "C" void kernel_launch(void* const* d_in, const int* in_sizes, int n_in,
                              void* d_out, int out_size, void* d_ws, size_t ws_size,
                              hipStream_t stream) {
  const float* inp      = (const float*)d_in[0];
  const float* hid      = (const float*)d_in[1];
  const float* mem_bias = (const float*)d_in[2];
  const float* W_h2w    = (const float*)d_in[3];
  const float* W_i2w    = (const float*)d_in[4];
  const float* W_m2w    = (const float*)d_in[5];
  const float* W_u2w    = (const float*)d_in[6];
  const float* W_h2g    = (const float*)d_in[7];
  const float* W_i2g    = (const float*)d_in[8];
  const float* W_r2g    = (const float*)d_in[9];
  const float* W_h2ab   = (const float*)d_in[10];
  const float* W_i2ab   = (const float*)d_in[11];
  const float* W_r2ab   = (const float*)d_in[12];
  const float* W_h2c    = (const float*)d_in[13];
  const float* W_i2c    = (const float*)d_in[14];
  const float* W_r2c    = (const float*)d_in[15];
  const float* atten    = (const float*)d_in[16];
  const float* W_h2tau  = (const float*)d_in[17];
  const float* b_h2tau  = (const float*)d_in[18];
  const float* W_h2m    = (const float*)d_in[19];
  float* out = (float*)d_out;

  char* base = (char*)d_ws;
  size_t off = 0;
  auto alloc = [&](size_t elems) -> void* {
    void* p = (void*)(base + off);
    off += ((elems * 4 + 255) / 256) * 256;
    return p;
  };
  float* icat     = (float*)alloc((size_t)LL * BB * WC);
  float* Wicat    = (float*)alloc((size_t)ID * WC);
  float* Wcat     = (float*)alloc((size_t)HD * WC);
  float* addrW    = (float*)alloc((size_t)NS * AC);
  float* addrWT   = (float*)alloc((size_t)NS * AC);
  float* hbuf     = (float*)alloc((size_t)BB * HD);
  float* ccbuf    = (float*)alloc((size_t)BB * HD);
  float* w_sum    = (float*)alloc((size_t)BB * NS);
  float* u2w      = (float*)alloc((size_t)BB * AC);
  float* valHist  = (float*)alloc((size_t)BB * LL * CCd);
  float* valWHist = (float*)alloc((size_t)BB * LL * AC);
  float* hcat     = (float*)alloc((size_t)BB * WC);
  float* zbuf     = (float*)alloc((size_t)BB * NS);
  float* gmaxv    = (float*)alloc((size_t)BB * 2);
  int*   gmaxi    = (int*)alloc((size_t)BB * 2);
  int*   writePos = (int*)alloc((size_t)BB * LL);
  int*   lastWriter = (int*)alloc((size_t)BB * NS);
  unsigned int* bar_ctr = (unsigned int*)alloc(64);

  hipLaunchKernelGGL(pack_wcat, dim3((HD * WC + 255) / 256), dim3(256), 0, stream,
                     W_h2c, W_h2w, W_h2g, W_h2ab, W_h2tau, Wcat);
  hipLaunchKernelGGL(pack_wicat, dim3((ID * WC + 255) / 256), dim3(256), 0, stream,
                     W_i2c, W_i2w, W_i2g, W_i2ab, Wicat);
  hipLaunchKernelGGL(addrw_kernel, dim3((NS * AC + 255) / 256), dim3(256), 0, stream,
                     mem_bias, W_m2w, addrW, addrWT);
  hipLaunchKernelGGL(init_kernel, dim3((BB * HD + 255) / 256), dim3(256), 0, stream,
                     hid, hbuf, ccbuf, w_sum, lastWriter, u2w, bar_ctr);
  hipLaunchKernelGGL(gemm_big, dim3((LL * BB) / 128, WC / 64), dim3(256), 0, stream,
                     inp, Wicat, icat);
  hipLaunchKernelGGL(persist_kernel, dim3(GRID_P), dim3(512), 0, stream,
                     icat, Wcat, addrW, addrWT, atten, mem_bias,
                     W_r2g, W_r2ab, W_r2c, W_h2m, W_m2w, W_u2w, b_h2tau,
                     hbuf, ccbuf, w_sum, u2w, valHist, valWHist,
                     lastWriter, writePos, hcat, zbuf, gmaxv, gmaxi,
                     bar_ctr, out);
}

// Round 5
// 5682.053 us; speedup vs baseline: 1.3020x; 1.3020x over previous
//
#include <hip/hip_runtime.h>
#include <hip/hip_bf16.h>
#include <math.h>

// ---------------------------------------------------------------------------
// DecoderTARDIS forward, fp32, persistent kernel v3.
// Round-4 lesson: phases are ~30us/step; the old single-line spin barrier was
// ~65us x 96. New: counter+flag split barrier (sleep-backoff, read-only spin),
// 128 blocks, 2 phases/step (A: weight-stationary GEMM + val/u2w; LS: fused
// logits/gumbel/argmax/select/LSTM per batch). 64 barriers total.
// ---------------------------------------------------------------------------

static constexpr int LL    = 32;
static constexpr int BB    = 128;
static constexpr int ID    = 512;
static constexpr int HD    = 1024;
static constexpr int NS    = 512;
static constexpr int AA    = 128;
static constexpr int CCd   = 128;
static constexpr int AC    = 256;
static constexpr int WC    = 1408;   // packed cols, padded to 88*16
static constexpr int COL_W0  = 1024;
static constexpr int COL_G0  = 1280;
static constexpr int COL_AB0 = 1283;
static constexpr int COL_TAU = 1285;
static constexpr int NBLK  = 128;    // persistent blocks
static constexpr int ABLK  = 88;     // GEMM blocks in phase A (16 cols each)

// ------------------------------ threefry -----------------------------------
__device__ __forceinline__ uint32_t rotl32(uint32_t x, uint32_t r) {
  return (x << r) | (x >> (32u - r));
}

__device__ __forceinline__ void threefry2x32(uint32_t k0, uint32_t k1,
                                             uint32_t x0, uint32_t x1,
                                             uint32_t& o0, uint32_t& o1) {
  uint32_t ks0 = k0, ks1 = k1, ks2 = 0x1BD11BDAu ^ k0 ^ k1;
  x0 += ks0; x1 += ks1;
#define TFR(r) { x0 += x1; x1 = rotl32(x1, r); x1 ^= x0; }
  TFR(13u) TFR(15u) TFR(26u) TFR(6u)   x0 += ks1; x1 += ks2 + 1u;
  TFR(17u) TFR(29u) TFR(16u) TFR(24u)  x0 += ks2; x1 += ks0 + 2u;
  TFR(13u) TFR(15u) TFR(26u) TFR(6u)   x0 += ks0; x1 += ks1 + 3u;
  TFR(17u) TFR(29u) TFR(16u) TFR(24u)  x0 += ks1; x1 += ks2 + 4u;
  TFR(13u) TFR(15u) TFR(26u) TFR(6u)   x0 += ks2; x1 += ks0 + 5u;
#undef TFR
  o0 = x0; o1 = x1;
}

__device__ __forceinline__ float bits_to_gumbel(uint32_t bits) {
  uint32_t v = (bits >> 9) | 0x3F800000u;
  float f = __uint_as_float(v) - 1.0f;
  if (f <= 0.0f) f = 1.17549435e-38f;
  return -logf(-logf(f));
}

__device__ __forceinline__ float fast_tanh(float x) {
  float e = __expf(2.0f * x);
  return 1.0f - 2.0f / (e + 1.0f);
}

// ---------------- grid barrier: counter + flag, sleep backoff --------------
__device__ __forceinline__ void gbar(unsigned int* cnt, unsigned int* flag,
                                     unsigned int& epoch) {
  __syncthreads();
  if (threadIdx.x == 0) {
    epoch++;
    unsigned int old = __hip_atomic_fetch_add(cnt, 1u, __ATOMIC_ACQ_REL,
                                              __HIP_MEMORY_SCOPE_AGENT);
    if (old == epoch * NBLK - 1u) {
      __hip_atomic_store(flag, epoch, __ATOMIC_RELEASE, __HIP_MEMORY_SCOPE_AGENT);
    } else {
      while (__hip_atomic_load(flag, __ATOMIC_RELAXED, __HIP_MEMORY_SCOPE_AGENT) < epoch) {
        __builtin_amdgcn_s_sleep(16);
      }
      (void)__hip_atomic_load(flag, __ATOMIC_ACQUIRE, __HIP_MEMORY_SCOPE_AGENT);
    }
  }
  __syncthreads();
}

// ------------------------------ prologue -----------------------------------
__global__ void pack_wcat(const float* __restrict__ Wh2c, const float* __restrict__ Wh2w,
                          const float* __restrict__ Wh2g, const float* __restrict__ Wh2ab,
                          const float* __restrict__ Wh2tau, float* __restrict__ Wcat) {
  int idx = blockIdx.x * blockDim.x + threadIdx.x;
  if (idx >= HD * WC) return;
  int k = idx / WC, c = idx % WC;
  float v = 0.0f;
  if (c < 1024)       v = Wh2c[(size_t)k * HD + c];
  else if (c < 1280)  v = Wh2w[(size_t)k * AC + (c - 1024)];
  else if (c < 1283)  v = Wh2g[k * 3 + (c - 1280)];
  else if (c < 1285)  v = Wh2ab[k * 2 + (c - 1283)];
  else if (c == 1285) v = Wh2tau[k];
  Wcat[idx] = v;
}

__global__ void pack_wicat(const float* __restrict__ Wi2c, const float* __restrict__ Wi2w,
                           const float* __restrict__ Wi2g, const float* __restrict__ Wi2ab,
                           float* __restrict__ Wicat) {
  int idx = blockIdx.x * blockDim.x + threadIdx.x;
  if (idx >= ID * WC) return;
  int k = idx / WC, c = idx % WC;
  float v = 0.0f;
  if (c < 1024)      v = Wi2c[(size_t)k * HD + c];
  else if (c < 1280) v = Wi2w[(size_t)k * AC + (c - 1024)];
  else if (c < 1283) v = Wi2g[k * 3 + (c - 1280)];
  else if (c < 1285) v = Wi2ab[k * 2 + (c - 1283)];
  Wicat[idx] = v;
}

__global__ void addrw_kernel(const float* __restrict__ mem_bias,
                             const float* __restrict__ Wm2w,
                             float* __restrict__ addrW, float* __restrict__ addrWT) {
  int idx = blockIdx.x * blockDim.x + threadIdx.x;
  if (idx >= NS * AC) return;
  int n = idx / AC, m = idx % AC;
  float acc = 0.0f;
  for (int k = 0; k < AA; k++) acc += mem_bias[(size_t)n * AC + k] * Wm2w[(size_t)k * AC + m];
  addrW[(size_t)n * AC + m] = acc;
  addrWT[(size_t)m * NS + n] = acc;
}

__global__ void init_kernel(const float* __restrict__ hid, float* __restrict__ h,
                            float* __restrict__ cc, float* __restrict__ w_sum,
                            int* __restrict__ lastWriter, float* __restrict__ u2w,
                            unsigned int* __restrict__ bar) {
  int idx = blockIdx.x * blockDim.x + threadIdx.x;
  if (idx < BB * HD) { h[idx] = hid[idx]; cc[idx] = 0.0f; }
  if (idx < BB * NS) { w_sum[idx] = 0.0f; lastWriter[idx] = -1; }
  if (idx < BB * AC) { u2w[idx] = 0.0f; }
  if (idx < 512) bar[idx] = 0u;   // counter line + flag line
}

// -------- big fp32 GEMM (icat = inp @ Wicat), 128x64 tile, 8x4/thread ------
__global__ __launch_bounds__(256) void gemm_big(const float* __restrict__ A,
                                                const float* __restrict__ W,
                                                float* __restrict__ C) {
  __shared__ float sA[32][132];
  __shared__ float sB[32][68];
  const int tx = threadIdx.x & 15, ty = threadIdx.x >> 4;
  const int m0 = blockIdx.x * 128, n0 = blockIdx.y * 64;
  float acc[8][4] = {};
  for (int k0 = 0; k0 < ID; k0 += 32) {
    for (int i = threadIdx.x; i < 128 * 32; i += 256) {
      int r = i >> 5, kk = i & 31;
      sA[kk][r] = A[(size_t)(m0 + r) * ID + k0 + kk];
    }
    for (int i = threadIdx.x; i < 32 * 64; i += 256) {
      int kk = i >> 6, c = i & 63;
      sB[kk][c] = W[(size_t)(k0 + kk) * WC + n0 + c];
    }
    __syncthreads();
#pragma unroll
    for (int kk = 0; kk < 32; ++kk) {
      float4 a0 = *(const float4*)&sA[kk][ty * 8];
      float4 a1 = *(const float4*)&sA[kk][ty * 8 + 4];
      float4 b0 = *(const float4*)&sB[kk][tx * 4];
      float ar[8] = {a0.x, a0.y, a0.z, a0.w, a1.x, a1.y, a1.z, a1.w};
      float br[4] = {b0.x, b0.y, b0.z, b0.w};
#pragma unroll
      for (int i2 = 0; i2 < 8; ++i2)
#pragma unroll
        for (int j2 = 0; j2 < 4; ++j2)
          acc[i2][j2] = fmaf(ar[i2], br[j2], acc[i2][j2]);
    }
    __syncthreads();
  }
#pragma unroll
  for (int i2 = 0; i2 < 8; ++i2) {
    float4 st = make_float4(acc[i2][0], acc[i2][1], acc[i2][2], acc[i2][3]);
    *(float4*)&C[(size_t)(m0 + ty * 8 + i2) * WC + n0 + tx * 4] = st;
  }
}

// ------------------------------ persistent kernel --------------------------
struct SMemA { float hst[128][68]; };                       // 34.8 KB h-chunk
struct SMemL { float bias[AC]; float att[AC]; float zl[NS]; float rs[AC]; };
struct SMemV { float hls[HD]; float vhalf[512]; float vs[CCd]; float zn[512]; };
union SMemU { SMemA a; SMemL l; SMemV v; };

__global__ __launch_bounds__(512) void persist_kernel(
    const float* __restrict__ icat, const float* __restrict__ Wcat,
    const float* __restrict__ addrW, const float* __restrict__ addrWT,
    const float* __restrict__ atten, const float* __restrict__ mem_bias,
    const float* __restrict__ Wr2g, const float* __restrict__ Wr2ab,
    const float* __restrict__ Wr2c, const float* __restrict__ Wh2m,
    const float* __restrict__ Wm2w, const float* __restrict__ Wu2w,
    const float* __restrict__ b_h2tau,
    float* hbuf, float* ccbuf, float* w_sum, float* u2w,
    float* valHist, float* valWHist, int* lastWriter, int* writePos,
    float* hcat, unsigned int* bar_cnt, unsigned int* bar_flag, float* out) {
  const int blk = blockIdx.x, tid = threadIdx.x;
  const int lane = tid & 63, wv = tid >> 6;
  __shared__ float smW[16][1028];      // persistent Wcat slice, 64.25 KB
  __shared__ SMemU sm;
  __shared__ float redv[8]; __shared__ int redi[8];
  __shared__ float gdot[5], s_fio[3], s_ab[2], s_tau, s_zmax;
  __shared__ int s_ns;
  unsigned int epoch = 0;

  uint32_t k1a, k1b, k2a, k2b;
  threefry2x32(0u, 42u, 0u, 0u, k1a, k1b);
  threefry2x32(0u, 42u, 0u, 1u, k2a, k2b);

  // one-time: this block's 16 Wcat columns -> LDS
  if (blk < ABLK) {
    const int n0 = blk * 16;
    for (int i = tid; i < 16 * 1024; i += 512) {
      int c = i & 15, k = i >> 4;
      smW[c][k] = Wcat[(size_t)k * WC + n0 + c];
    }
  }
  __syncthreads();

  for (int t = 0; t < LL; ++t) {
    // ========== phase A: hcat GEMM (0..87) | val/valW/u2w (88..127) =========
    if (blk < ABLK) {
      const int c = tid & 15, rp = tid >> 4;   // 16 cols x 32 row-groups
      float acc[4] = {0.0f, 0.0f, 0.0f, 0.0f};
      for (int kc = 0; kc < HD; kc += 64) {
        __syncthreads();
#pragma unroll
        for (int ii = 0; ii < 4; ++ii) {
          int f = ii * 512 + tid;              // float4 idx in 128x16 chunk
          int row = f >> 4, k4 = f & 15;
          float4 vv = *(const float4*)&hbuf[(size_t)row * HD + kc + k4 * 4];
          *(float4*)&sm.a.hst[row][k4 * 4] = vv;
        }
        __syncthreads();
        const int kb = kc;
#pragma unroll
        for (int k4 = 0; k4 < 16; ++k4) {
          float4 w4 = *(const float4*)&smW[c][kb + k4 * 4];
#pragma unroll
          for (int j = 0; j < 4; ++j) {
            float4 h4 = *(const float4*)&sm.a.hst[rp * 4 + j][k4 * 4];
            acc[j] = fmaf(h4.x, w4.x, fmaf(h4.y, w4.y, fmaf(h4.z, w4.z, fmaf(h4.w, w4.w, acc[j]))));
          }
        }
      }
#pragma unroll
      for (int j = 0; j < 4; ++j)
        hcat[(size_t)(rp * 4 + j) * WC + blk * 16 + c] = acc[j];
    } else {
      const int i0 = blk - ABLK;               // 40 helper blocks
      for (int rep = 0; rep < 4; ++rep) {
        const int b = i0 + 40 * rep;
        if (b >= BB) break;
        if (t > 0) {
          for (int k = tid; k < HD; k += 512) sm.v.hls[k] = hbuf[(size_t)b * HD + k];
          __syncthreads();
          {
            int c = tid & 127, q = tid >> 7;
            const float* wp = Wh2m + c;
            float acc = 0.0f;
            int kb = q * 256;
#pragma unroll 4
            for (int k = kb; k < kb + 256; ++k) acc = fmaf(sm.v.hls[k], wp[(size_t)k * CCd], acc);
            sm.v.vhalf[tid] = acc;
          }
          __syncthreads();
          if (tid < CCd) {
            float val = sm.v.vhalf[tid] + sm.v.vhalf[tid + 128] + sm.v.vhalf[tid + 256] + sm.v.vhalf[tid + 384];
            sm.v.vs[tid] = val;
            valHist[((size_t)b * LL + (t - 1)) * CCd + tid] = val;
          }
          __syncthreads();
          {
            int m = tid & 255, h2 = tid >> 8;
            float acc = 0.0f;
            int cb = h2 * 64;
#pragma unroll 4
            for (int cix = cb; cix < cb + 64; ++cix)
              acc = fmaf(sm.v.vs[cix], Wm2w[(size_t)(AA + cix) * AC + m], acc);
            sm.v.zn[tid] = acc;
          }
          __syncthreads();
          if (tid < AC) valWHist[((size_t)b * LL + (t - 1)) * AC + tid] = sm.v.zn[tid] + sm.v.zn[tid + 256];
          __syncthreads();
        }
        {  // u2w(t) = layernorm(w_sum) @ Wu2w
          float v = w_sum[(size_t)b * NS + tid];
          float ssum = v;
          for (int off = 32; off; off >>= 1) ssum += __shfl_down(ssum, off, 64);
          if (lane == 0) redv[wv] = ssum;
          __syncthreads();
          float mu = (redv[0] + redv[1] + redv[2] + redv[3] + redv[4] + redv[5] + redv[6] + redv[7]) / (float)NS;
          __syncthreads();
          float d = (v - mu) * (v - mu);
          for (int off = 32; off; off >>= 1) d += __shfl_down(d, off, 64);
          if (lane == 0) redv[wv] = d;
          __syncthreads();
          float var = (redv[0] + redv[1] + redv[2] + redv[3] + redv[4] + redv[5] + redv[6] + redv[7]) / (float)NS;
          float rsq = rsqrtf(var + 1e-5f);
          sm.v.zn[tid] = (v - mu) * rsq;
          __syncthreads();
          {
            int m = tid & 255, h2 = tid >> 8;
            float acc = 0.0f;
            int kb2 = h2 * 256;
#pragma unroll 4
            for (int k = kb2; k < kb2 + 256; ++k) acc = fmaf(sm.v.zn[k], Wu2w[(size_t)k * AC + m], acc);
            sm.v.vhalf[tid] = acc;
          }
          __syncthreads();
          if (tid < AC) u2w[(size_t)b * AC + tid] = sm.v.vhalf[tid] + sm.v.vhalf[tid + 256];
          __syncthreads();
        }
      }
    }
    gbar(bar_cnt, bar_flag, epoch);

    // ========== phase LS: per-batch fused (all 128 blocks) ==================
    {
      const int b = blk;
      const float* icrow = icat + (size_t)(t * BB + b) * WC;
      if (tid < AC) {
        sm.l.bias[tid] = hcat[(size_t)b * WC + COL_W0 + tid] + icrow[COL_W0 + tid] +
                         u2w[(size_t)b * AC + tid];
        sm.l.att[tid] = atten[tid];
      }
      __syncthreads();
      {  // logits for n = tid (all 512)
        float p = 0.0f;
        const float* awc = addrWT + tid;
#pragma unroll 8
        for (int k = 0; k < AC; ++k)
          p = fmaf(fast_tanh(sm.l.bias[k] + awc[(size_t)k * NS]), sm.l.att[k], p);
        sm.l.zl[tid] = p;
      }
      __syncthreads();
      for (int j = wv; j < t; j += 8) {  // corrections for written slots
        int n2 = writePos[b * LL + j];
        int s = lastWriter[b * NS + n2];
        const float* dw = valWHist + ((size_t)b * LL + s) * AC;
        const float* aw = addrW + (size_t)n2 * AC;
        float q = 0.0f;
        for (int k = lane; k < AC; k += 64)
          q = fmaf(fast_tanh(sm.l.bias[k] + aw[k] + dw[k]), sm.l.att[k], q);
        for (int off = 32; off; off >>= 1) q += __shfl_down(q, off, 64);
        if (lane == 0) sm.l.zl[n2] = q;
      }
      __syncthreads();
      float zg;
      {
        uint32_t gi = (uint32_t)((t * BB + b) * NS + tid);
        uint32_t o0, o1; threefry2x32(k1a, k1b, 0u, gi, o0, o1);
        zg = sm.l.zl[tid] + bits_to_gumbel(o0 ^ o1);
      }
      {  // argmax (value, index) over 512
        float v = zg; int ix = tid;
        for (int off = 32; off; off >>= 1) {
          float vo = __shfl_down(v, off, 64); int io = __shfl_down(ix, off, 64);
          if (vo > v || (vo == v && io < ix)) { v = vo; ix = io; }
        }
        if (lane == 0) { redv[wv] = v; redi[wv] = ix; }
      }
      __syncthreads();
      if (tid == 0) {
        float v = redv[0]; int ix = redi[0];
        for (int w2 = 1; w2 < 8; ++w2) {
          if (redv[w2] > v || (redv[w2] == v && redi[w2] < ix)) { v = redv[w2]; ix = redi[w2]; }
        }
        s_zmax = v; s_ns = ix;
        float x = hcat[(size_t)b * WC + COL_TAU] + b_h2tau[0];
        s_tau = fmaxf(x, 0.0f) + log1pf(expf(-fabsf(x))) + 1.0f;
      }
      __syncthreads();
      const float tau = s_tau, zmax = s_zmax; const int ns = s_ns;
      {
        float e = expf((zg - zmax) / tau);
        for (int off = 32; off; off >>= 1) e += __shfl_down(e, off, 64);
        if (lane == 0) redv[wv] = e;
      }
      __syncthreads();
      const float D = redv[0] + redv[1] + redv[2] + redv[3] + redv[4] + redv[5] + redv[6] + redv[7];
      const float ystar = 1.0f / D;
      const float ws = (1.0f - ystar) + ystar;
      if (tid < AC) {
        int sW_ = lastWriter[b * NS + ns];
        float mv = (tid < AA) ? mem_bias[(size_t)ns * AC + tid]
                 : ((sW_ >= 0) ? valHist[((size_t)b * LL + sW_) * CCd + (tid - AA)] : 0.0f);
        sm.l.rs[tid] = ws * mv;
      }
      __syncthreads();
      if (tid == 0) {  // bookkeeping AFTER r-gather read lastWriter
        int pos = (t * LL < NS) ? (t * LL) : ns;
        writePos[b * LL + t] = pos;
        lastWriter[b * NS + pos] = t;
        w_sum[(size_t)b * NS + ns] += ws;
      }
      if (tid < 160) {
        int j = tid >> 5, l = tid & 31;
        float p = 0.0f;
        if (j < 3) { for (int k = l; k < AC; k += 32) p += sm.l.rs[k] * Wr2g[k * 3 + j]; }
        else { int jj = j - 3; for (int k = l; k < AC; k += 32) p += sm.l.rs[k] * Wr2ab[k * 2 + jj]; }
        for (int off = 16; off; off >>= 1) p += __shfl_down(p, off, 32);
        if (l == 0) gdot[j] = p;
      }
      __syncthreads();
      if (tid < 3) {
        float x = hcat[(size_t)b * WC + COL_G0 + tid] + icrow[COL_G0 + tid] + gdot[tid];
        s_fio[tid] = 1.0f / (1.0f + expf(-x));
      } else if (tid < 5) {
        int j = tid - 3;
        float x = hcat[(size_t)b * WC + COL_AB0 + j] + icrow[COL_AB0 + j] + gdot[tid];
        uint32_t i1 = (uint32_t)(((t * BB + b) * 2 + j) * 2);
        uint32_t o0, o1;
        threefry2x32(k2a, k2b, 0u, i1, o0, o1);     float g1 = bits_to_gumbel(o0 ^ o1);
        threefry2x32(k2a, k2b, 0u, i1 + 1, o0, o1); float g2 = bits_to_gumbel(o0 ^ o1);
        s_ab[j] = (x + g1 - g2) > 0.0f ? 1.0f : 0.0f;
      }
      __syncthreads();
      const float fg = s_fio[0], ig = s_fio[1], og = s_fio[2];
      const float alpha = s_ab[0], beta = s_ab[1];
      const int c0 = tid * 2;
      {
        float r0 = 0.0f, r1 = 0.0f;
#pragma unroll 4
        for (int k = 0; k < AC; ++k) {
          float rk = sm.l.rs[k];
          float2 w2 = *(const float2*)&Wr2c[(size_t)k * HD + c0];
          r0 = fmaf(rk, w2.x, r0); r1 = fmaf(rk, w2.y, r1);
        }
        float2 hc2 = *(const float2*)&hcat[(size_t)b * WC + c0];
        float2 ic2 = *(const float2*)&icrow[c0];
        float2 cc2 = *(const float2*)&ccbuf[(size_t)b * HD + c0];
        float a0 = beta * hc2.x + ic2.x + alpha * r0;
        float a1 = beta * hc2.y + ic2.y + alpha * r1;
        float cn0 = fg * cc2.x + ig * tanhf(a0);
        float cn1 = fg * cc2.y + ig * tanhf(a1);
        float hn0 = og * tanhf(cn0), hn1 = og * tanhf(cn1);
        *(float2*)&ccbuf[(size_t)b * HD + c0] = make_float2(cn0, cn1);
        *(float2*)&hbuf[(size_t)b * HD + c0] = make_float2(hn0, hn1);
        *(float2*)&out[((size_t)t * BB + b) * HD + c0] = make_float2(hn0, hn1);
      }
    }
    if (t + 1 < LL) gbar(bar_cnt, bar_flag, epoch);
  }
}

// ------------------------------ host ---------------------------------------
extern "C" void kernel_launch(void* const* d_in, const int* in_sizes, int n_in,
                              void* d_out, int out_size, void* d_ws, size_t ws_size,
                              hipStream_t stream) {
  const float* inp      = (const float*)d_in[0];
  const float* hid      = (const float*)d_in[1];
  const float* mem_bias = (const float*)d_in[2];
  const float* W_h2w    = (const float*)d_in[3];
  const float* W_i2w    = (const float*)d_in[4];
  const float* W_m2w    = (const float*)d_in[5];
  const float* W_u2w    = (const float*)d_in[6];
  const float* W_h2g    = (const float*)d_in[7];
  const float* W_i2g    = (const float*)d_in[8];
  const float* W_r2g    = (const float*)d_in[9];
  const float* W_h2ab   = (const float*)d_in[10];
  const float* W_i2ab   = (const float*)d_in[11];
  const float* W_r2ab   = (const float*)d_in[12];
  const float* W_h2c    = (const float*)d_in[13];
  const float* W_i2c    = (const float*)d_in[14];
  const float* W_r2c    = (const float*)d_in[15];
  const float* atten    = (const float*)d_in[16];
  const float* W_h2tau  = (const float*)d_in[17];
  const float* b_h2tau  = (const float*)d_in[18];
  const float* W_h2m    = (const float*)d_in[19];
  float* out = (float*)d_out;

  char* base = (char*)d_ws;
  size_t off = 0;
  auto alloc = [&](size_t elems) -> void* {
    void* p = (void*)(base + off);
    off += ((elems * 4 + 255) / 256) * 256;
    return p;
  };
  float* icat     = (float*)alloc((size_t)LL * BB * WC);
  float* Wicat    = (float*)alloc((size_t)ID * WC);
  float* Wcat     = (float*)alloc((size_t)HD * WC);
  float* addrW    = (float*)alloc((size_t)NS * AC);
  float* addrWT   = (float*)alloc((size_t)NS * AC);
  float* hbuf     = (float*)alloc((size_t)BB * HD);
  float* ccbuf    = (float*)alloc((size_t)BB * HD);
  float* w_sum    = (float*)alloc((size_t)BB * NS);
  float* u2w      = (float*)alloc((size_t)BB * AC);
  float* valHist  = (float*)alloc((size_t)BB * LL * CCd);
  float* valWHist = (float*)alloc((size_t)BB * LL * AC);
  float* hcat     = (float*)alloc((size_t)BB * WC);
  int*   writePos = (int*)alloc((size_t)BB * LL);
  int*   lastWriter = (int*)alloc((size_t)BB * NS);
  unsigned int* bar = (unsigned int*)alloc(512);   // [0]=counter, [256]=flag

  hipLaunchKernelGGL(pack_wcat, dim3((HD * WC + 255) / 256), dim3(256), 0, stream,
                     W_h2c, W_h2w, W_h2g, W_h2ab, W_h2tau, Wcat);
  hipLaunchKernelGGL(pack_wicat, dim3((ID * WC + 255) / 256), dim3(256), 0, stream,
                     W_i2c, W_i2w, W_i2g, W_i2ab, Wicat);
  hipLaunchKernelGGL(addrw_kernel, dim3((NS * AC + 255) / 256), dim3(256), 0, stream,
                     mem_bias, W_m2w, addrW, addrWT);
  hipLaunchKernelGGL(init_kernel, dim3((BB * HD + 255) / 256), dim3(256), 0, stream,
                     hid, hbuf, ccbuf, w_sum, lastWriter, u2w, bar);
  hipLaunchKernelGGL(gemm_big, dim3((LL * BB) / 128, WC / 64), dim3(256), 0, stream,
                     inp, Wicat, icat);
  hipLaunchKernelGGL(persist_kernel, dim3(NBLK), dim3(512), 0, stream,
                     icat, Wcat, addrW, addrWT, atten, mem_bias,
                     W_r2g, W_r2ab, W_r2c, W_h2m, W_m2w, W_u2w, b_h2tau,
                     hbuf, ccbuf, w_sum, u2w, valHist, valWHist,
                     lastWriter, writePos, hcat, bar, bar + 256, out);
}

// Round 6
// 5168.068 us; speedup vs baseline: 1.4314x; 1.0995x over previous
//
#include <hip/hip_runtime.h>
#include <hip/hip_bf16.h>
#include <math.h>

// ---------------------------------------------------------------------------
// DecoderTARDIS forward, fp32, persistent kernel v4 — FENCE-FREE barriers.
// Round-5 lesson: ~80us/barrier regardless of spin protocol = agent-scope
// acquire/release cache maintenance wiping per-XCD L2 every barrier, forcing
// all weight streams back to LLC. v4: relaxed atomics only + explicit
// s_waitcnt vmcnt(0) per wave; cross-block data (hbuf, hcat) uses relaxed
// agent-scope atomic ld/st (coherence-point access, no cache wipe); weights
// stay normally cached (L2 warm). val/valW/u2w are block-private now.
// ---------------------------------------------------------------------------

static constexpr int LL    = 32;
static constexpr int BB    = 128;
static constexpr int ID    = 512;
static constexpr int HD    = 1024;
static constexpr int NS    = 512;
static constexpr int AA    = 128;
static constexpr int CCd   = 128;
static constexpr int AC    = 256;
static constexpr int WC    = 1408;
static constexpr int COL_W0  = 1024;
static constexpr int COL_G0  = 1280;
static constexpr int COL_AB0 = 1283;
static constexpr int COL_TAU = 1285;
static constexpr int NBLK  = 128;
static constexpr int ABLK  = 88;     // GEMM blocks in phase A (16 cols each)

// ------------------------------ threefry -----------------------------------
__device__ __forceinline__ uint32_t rotl32(uint32_t x, uint32_t r) {
  return (x << r) | (x >> (32u - r));
}

__device__ __forceinline__ void threefry2x32(uint32_t k0, uint32_t k1,
                                             uint32_t x0, uint32_t x1,
                                             uint32_t& o0, uint32_t& o1) {
  uint32_t ks0 = k0, ks1 = k1, ks2 = 0x1BD11BDAu ^ k0 ^ k1;
  x0 += ks0; x1 += ks1;
#define TFR(r) { x0 += x1; x1 = rotl32(x1, r); x1 ^= x0; }
  TFR(13u) TFR(15u) TFR(26u) TFR(6u)   x0 += ks1; x1 += ks2 + 1u;
  TFR(17u) TFR(29u) TFR(16u) TFR(24u)  x0 += ks2; x1 += ks0 + 2u;
  TFR(13u) TFR(15u) TFR(26u) TFR(6u)   x0 += ks0; x1 += ks1 + 3u;
  TFR(17u) TFR(29u) TFR(16u) TFR(24u)  x0 += ks1; x1 += ks2 + 4u;
  TFR(13u) TFR(15u) TFR(26u) TFR(6u)   x0 += ks2; x1 += ks0 + 5u;
#undef TFR
  o0 = x0; o1 = x1;
}

__device__ __forceinline__ float bits_to_gumbel(uint32_t bits) {
  uint32_t v = (bits >> 9) | 0x3F800000u;
  float f = __uint_as_float(v) - 1.0f;
  if (f <= 0.0f) f = 1.17549435e-38f;
  return -logf(-logf(f));
}

__device__ __forceinline__ float fast_tanh(float x) {
  float e = __expf(2.0f * x);
  return 1.0f - 2.0f / (e + 1.0f);
}

// --------------- coherent (agent-scope, relaxed) access helpers ------------
__device__ __forceinline__ float cohl(const float* p) {
  return __hip_atomic_load(p, __ATOMIC_RELAXED, __HIP_MEMORY_SCOPE_AGENT);
}
__device__ __forceinline__ void cohs(float* p, float v) {
  __hip_atomic_store(p, v, __ATOMIC_RELAXED, __HIP_MEMORY_SCOPE_AGENT);
}
__device__ __forceinline__ float2 cohl2(const float* p) {
  unsigned long long u = __hip_atomic_load((const unsigned long long*)p,
                                           __ATOMIC_RELAXED, __HIP_MEMORY_SCOPE_AGENT);
  float2 r; __builtin_memcpy(&r, &u, 8); return r;
}
__device__ __forceinline__ void cohs2(float* p, float2 v) {
  unsigned long long u; __builtin_memcpy(&u, &v, 8);
  __hip_atomic_store((unsigned long long*)p, u, __ATOMIC_RELAXED, __HIP_MEMORY_SCOPE_AGENT);
}

// ---------------- grid barrier: relaxed atomics + vmcnt drain --------------
__device__ __forceinline__ void gbar(unsigned int* cnt, unsigned int* flag,
                                     unsigned int& epoch) {
  // every wave drains its own outstanding global stores (ack at coherence pt)
  asm volatile("s_waitcnt vmcnt(0)" ::: "memory");
  __syncthreads();
  if (threadIdx.x == 0) {
    epoch++;
    unsigned int old = __hip_atomic_fetch_add(cnt, 1u, __ATOMIC_RELAXED,
                                              __HIP_MEMORY_SCOPE_AGENT);
    if (old == epoch * NBLK - 1u) {
      __hip_atomic_store(flag, epoch, __ATOMIC_RELAXED, __HIP_MEMORY_SCOPE_AGENT);
    } else {
      while (__hip_atomic_load(flag, __ATOMIC_RELAXED, __HIP_MEMORY_SCOPE_AGENT) < epoch) {
        __builtin_amdgcn_s_sleep(8);
      }
    }
  }
  __syncthreads();
}

// ------------------------------ prologue -----------------------------------
__global__ void pack_wcat(const float* __restrict__ Wh2c, const float* __restrict__ Wh2w,
                          const float* __restrict__ Wh2g, const float* __restrict__ Wh2ab,
                          const float* __restrict__ Wh2tau, float* __restrict__ Wcat) {
  int idx = blockIdx.x * blockDim.x + threadIdx.x;
  if (idx >= HD * WC) return;
  int k = idx / WC, c = idx % WC;
  float v = 0.0f;
  if (c < 1024)       v = Wh2c[(size_t)k * HD + c];
  else if (c < 1280)  v = Wh2w[(size_t)k * AC + (c - 1024)];
  else if (c < 1283)  v = Wh2g[k * 3 + (c - 1280)];
  else if (c < 1285)  v = Wh2ab[k * 2 + (c - 1283)];
  else if (c == 1285) v = Wh2tau[k];
  Wcat[idx] = v;
}

__global__ void pack_wicat(const float* __restrict__ Wi2c, const float* __restrict__ Wi2w,
                           const float* __restrict__ Wi2g, const float* __restrict__ Wi2ab,
                           float* __restrict__ Wicat) {
  int idx = blockIdx.x * blockDim.x + threadIdx.x;
  if (idx >= ID * WC) return;
  int k = idx / WC, c = idx % WC;
  float v = 0.0f;
  if (c < 1024)      v = Wi2c[(size_t)k * HD + c];
  else if (c < 1280) v = Wi2w[(size_t)k * AC + (c - 1024)];
  else if (c < 1283) v = Wi2g[k * 3 + (c - 1280)];
  else if (c < 1285) v = Wi2ab[k * 2 + (c - 1283)];
  Wicat[idx] = v;
}

__global__ void addrw_kernel(const float* __restrict__ mem_bias,
                             const float* __restrict__ Wm2w,
                             float* __restrict__ addrW, float* __restrict__ addrWT) {
  int idx = blockIdx.x * blockDim.x + threadIdx.x;
  if (idx >= NS * AC) return;
  int n = idx / AC, m = idx % AC;
  float acc = 0.0f;
  for (int k = 0; k < AA; k++) acc += mem_bias[(size_t)n * AC + k] * Wm2w[(size_t)k * AC + m];
  addrW[(size_t)n * AC + m] = acc;
  addrWT[(size_t)m * NS + n] = acc;
}

__global__ void init_kernel(const float* __restrict__ hid, float* __restrict__ hbuf,
                            unsigned int* __restrict__ bar) {
  int idx = blockIdx.x * blockDim.x + threadIdx.x;
  if (idx < BB * HD) hbuf[idx] = hid[idx];
  if (idx < 512) bar[idx] = 0u;
}

// -------- big fp32 GEMM (icat = inp @ Wicat), 128x64 tile, 8x4/thread ------
__global__ __launch_bounds__(256) void gemm_big(const float* __restrict__ A,
                                                const float* __restrict__ W,
                                                float* __restrict__ C) {
  __shared__ float sA[32][132];
  __shared__ float sB[32][68];
  const int tx = threadIdx.x & 15, ty = threadIdx.x >> 4;
  const int m0 = blockIdx.x * 128, n0 = blockIdx.y * 64;
  float acc[8][4] = {};
  for (int k0 = 0; k0 < ID; k0 += 32) {
    for (int i = threadIdx.x; i < 128 * 32; i += 256) {
      int r = i >> 5, kk = i & 31;
      sA[kk][r] = A[(size_t)(m0 + r) * ID + k0 + kk];
    }
    for (int i = threadIdx.x; i < 32 * 64; i += 256) {
      int kk = i >> 6, c = i & 63;
      sB[kk][c] = W[(size_t)(k0 + kk) * WC + n0 + c];
    }
    __syncthreads();
#pragma unroll
    for (int kk = 0; kk < 32; ++kk) {
      float4 a0 = *(const float4*)&sA[kk][ty * 8];
      float4 a1 = *(const float4*)&sA[kk][ty * 8 + 4];
      float4 b0 = *(const float4*)&sB[kk][tx * 4];
      float ar[8] = {a0.x, a0.y, a0.z, a0.w, a1.x, a1.y, a1.z, a1.w};
      float br[4] = {b0.x, b0.y, b0.z, b0.w};
#pragma unroll
      for (int i2 = 0; i2 < 8; ++i2)
#pragma unroll
        for (int j2 = 0; j2 < 4; ++j2)
          acc[i2][j2] = fmaf(ar[i2], br[j2], acc[i2][j2]);
    }
    __syncthreads();
  }
#pragma unroll
  for (int i2 = 0; i2 < 8; ++i2) {
    float4 st = make_float4(acc[i2][0], acc[i2][1], acc[i2][2], acc[i2][3]);
    *(float4*)&C[(size_t)(m0 + ty * 8 + i2) * WC + n0 + tx * 4] = st;
  }
}

// ------------------------------ persistent kernel --------------------------
struct SMemA { float hst[128][68]; };                           // 34.8 KB
struct SLS {
  float bias[AC]; float att[AC]; float zl[NS]; float rs[AC];
  float hls[HD]; float vhalf[512]; float vs[CCd]; float zn[512];
};                                                              // 13.8 KB
union SMemU { SMemA a; SLS ls; };

__global__ __launch_bounds__(512) void persist_kernel(
    const float* __restrict__ icat, const float* __restrict__ Wcat,
    const float* __restrict__ addrW, const float* __restrict__ addrWT,
    const float* __restrict__ atten, const float* __restrict__ mem_bias,
    const float* __restrict__ Wr2g, const float* __restrict__ Wr2ab,
    const float* __restrict__ Wr2c, const float* __restrict__ Wh2m,
    const float* __restrict__ Wm2w, const float* __restrict__ Wu2w,
    const float* __restrict__ b_h2tau,
    float* hbuf, float* hcat,
    float* valHist, float* valWHist, int* lastWriter, int* writePos,
    unsigned int* bar_cnt, unsigned int* bar_flag, float* out) {
  const int blk = blockIdx.x, tid = threadIdx.x;
  const int lane = tid & 63, wv = tid >> 6;
  __shared__ float smW[16][1028];      // persistent Wcat slice, 65.8 KB
  __shared__ SMemU sm;
  __shared__ float w_sumL[NS];         // block-private state in LDS
  __shared__ float u2wL[AC];
  __shared__ float ccL[HD];
  __shared__ float redv[8]; __shared__ int redi[8];
  __shared__ float gdot[5], s_fio[3], s_ab[2], s_tau, s_zmax;
  __shared__ int s_ns;
  unsigned int epoch = 0;

  uint32_t k1a, k1b, k2a, k2b;
  threefry2x32(0u, 42u, 0u, 0u, k1a, k1b);
  threefry2x32(0u, 42u, 0u, 1u, k2a, k2b);

  // per-block init (all private)
  for (int i = tid; i < HD; i += 512) ccL[i] = 0.0f;
  for (int i = tid; i < NS; i += 512) { w_sumL[i] = 0.0f; lastWriter[(size_t)blk * NS + i] = -1; }
  if (tid < AC) u2wL[tid] = 0.0f;
  // one-time: this block's 16 Wcat columns -> LDS (normal cached loads)
  if (blk < ABLK) {
    const int n0 = blk * 16;
    for (int i = tid; i < 16 * 1024; i += 512) {
      int c = i & 15, k = i >> 4;
      smW[c][k] = Wcat[(size_t)k * WC + n0 + c];
    }
  }
  __syncthreads();

  for (int t = 0; t < LL; ++t) {
    // ========== phase A: hcat = hbuf @ Wcat (blocks 0..87) ==================
    if (blk < ABLK) {
      const int c = tid & 15, rp = tid >> 4;
      float acc[4] = {0.0f, 0.0f, 0.0f, 0.0f};
      float2 pre[8];
#pragma unroll
      for (int ii = 0; ii < 8; ++ii) {           // preload chunk 0 (coherent)
        int f = ii * 512 + tid, row = f >> 5, k2 = f & 31;
        pre[ii] = cohl2(&hbuf[(size_t)row * HD + k2 * 2]);
      }
      for (int kc = 0; kc < HD; kc += 64) {
        __syncthreads();
#pragma unroll
        for (int ii = 0; ii < 8; ++ii) {
          int f = ii * 512 + tid, row = f >> 5, k2 = f & 31;
          *(float2*)&sm.a.hst[row][k2 * 2] = pre[ii];
        }
        __syncthreads();
        if (kc + 64 < HD) {
#pragma unroll
          for (int ii = 0; ii < 8; ++ii) {       // prefetch next chunk
            int f = ii * 512 + tid, row = f >> 5, k2 = f & 31;
            pre[ii] = cohl2(&hbuf[(size_t)row * HD + kc + 64 + k2 * 2]);
          }
        }
#pragma unroll
        for (int k4 = 0; k4 < 16; ++k4) {
          float4 w4 = *(const float4*)&smW[c][kc + k4 * 4];
#pragma unroll
          for (int j = 0; j < 4; ++j) {
            float4 h4 = *(const float4*)&sm.a.hst[rp * 4 + j][k4 * 4];
            acc[j] = fmaf(h4.x, w4.x, fmaf(h4.y, w4.y, fmaf(h4.z, w4.z, fmaf(h4.w, w4.w, acc[j]))));
          }
        }
      }
#pragma unroll
      for (int j = 0; j < 4; ++j)
        cohs(&hcat[(size_t)(rp * 4 + j) * WC + blk * 16 + c], acc[j]);
    }
    gbar(bar_cnt, bar_flag, epoch);

    // ========== phase LS: per-batch fused (all 128 blocks, b = blk) =========
    {
      const int b = blk;
      const float* icrow = icat + (size_t)(t * BB + b) * WC;
      if (tid < AC) {
        sm.ls.bias[tid] = cohl(&hcat[(size_t)b * WC + COL_W0 + tid]) +
                          icrow[COL_W0 + tid] + u2wL[tid];
        sm.ls.att[tid] = atten[tid];
      }
      __syncthreads();
      {  // logits for n = tid (addrWT normally cached -> warm L2)
        float p = 0.0f;
        const float* awc = addrWT + tid;
#pragma unroll 8
        for (int k = 0; k < AC; ++k)
          p = fmaf(fast_tanh(sm.ls.bias[k] + awc[(size_t)k * NS]), sm.ls.att[k], p);
        sm.ls.zl[tid] = p;
      }
      __syncthreads();
      for (int j = wv; j < t; j += 8) {  // corrections for written slots (private)
        int n2 = writePos[b * LL + j];
        int s = lastWriter[b * NS + n2];
        const float* dw = valWHist + ((size_t)b * LL + s) * AC;
        const float* aw = addrW + (size_t)n2 * AC;
        float q = 0.0f;
        for (int k = lane; k < AC; k += 64)
          q = fmaf(fast_tanh(sm.ls.bias[k] + aw[k] + dw[k]), sm.ls.att[k], q);
        for (int off = 32; off; off >>= 1) q += __shfl_down(q, off, 64);
        if (lane == 0) sm.ls.zl[n2] = q;
      }
      __syncthreads();
      float zg;
      {
        uint32_t gi = (uint32_t)((t * BB + b) * NS + tid);
        uint32_t o0, o1; threefry2x32(k1a, k1b, 0u, gi, o0, o1);
        zg = sm.ls.zl[tid] + bits_to_gumbel(o0 ^ o1);
      }
      {  // argmax over 512
        float v = zg; int ix = tid;
        for (int off = 32; off; off >>= 1) {
          float vo = __shfl_down(v, off, 64); int io = __shfl_down(ix, off, 64);
          if (vo > v || (vo == v && io < ix)) { v = vo; ix = io; }
        }
        if (lane == 0) { redv[wv] = v; redi[wv] = ix; }
      }
      __syncthreads();
      if (tid == 0) {
        float v = redv[0]; int ix = redi[0];
        for (int w2 = 1; w2 < 8; ++w2)
          if (redv[w2] > v || (redv[w2] == v && redi[w2] < ix)) { v = redv[w2]; ix = redi[w2]; }
        s_zmax = v; s_ns = ix;
        float x = cohl(&hcat[(size_t)b * WC + COL_TAU]) + b_h2tau[0];
        s_tau = fmaxf(x, 0.0f) + log1pf(expf(-fabsf(x))) + 1.0f;
      }
      __syncthreads();
      const float tau = s_tau, zmax = s_zmax; const int ns = s_ns;
      {
        float e = expf((zg - zmax) / tau);
        for (int off = 32; off; off >>= 1) e += __shfl_down(e, off, 64);
        if (lane == 0) redv[wv] = e;
      }
      __syncthreads();
      const float D = redv[0] + redv[1] + redv[2] + redv[3] + redv[4] + redv[5] + redv[6] + redv[7];
      const float ystar = 1.0f / D;
      const float ws = (1.0f - ystar) + ystar;
      if (tid < AC) {
        int sW_ = lastWriter[b * NS + ns];
        float mv = (tid < AA) ? mem_bias[(size_t)ns * AC + tid]
                 : ((sW_ >= 0) ? valHist[((size_t)b * LL + sW_) * CCd + (tid - AA)] : 0.0f);
        sm.ls.rs[tid] = ws * mv;
      }
      __syncthreads();
      if (tid == 0) {  // bookkeeping AFTER r-gather read lastWriter
        int pos = (t * LL < NS) ? (t * LL) : ns;
        writePos[b * LL + t] = pos;
        lastWriter[b * NS + pos] = t;
        w_sumL[ns] += ws;
      }
      if (tid < 160) {
        int j = tid >> 5, l = tid & 31;
        float p = 0.0f;
        if (j < 3) { for (int k = l; k < AC; k += 32) p += sm.ls.rs[k] * Wr2g[k * 3 + j]; }
        else { int jj = j - 3; for (int k = l; k < AC; k += 32) p += sm.ls.rs[k] * Wr2ab[k * 2 + jj]; }
        for (int off = 16; off; off >>= 1) p += __shfl_down(p, off, 32);
        if (l == 0) gdot[j] = p;
      }
      __syncthreads();
      if (tid < 3) {
        float x = cohl(&hcat[(size_t)b * WC + COL_G0 + tid]) + icrow[COL_G0 + tid] + gdot[tid];
        s_fio[tid] = 1.0f / (1.0f + expf(-x));
      } else if (tid < 5) {
        int j = tid - 3;
        float x = cohl(&hcat[(size_t)b * WC + COL_AB0 + j]) + icrow[COL_AB0 + j] + gdot[tid];
        uint32_t i1 = (uint32_t)(((t * BB + b) * 2 + j) * 2);
        uint32_t o0, o1;
        threefry2x32(k2a, k2b, 0u, i1, o0, o1);     float g1 = bits_to_gumbel(o0 ^ o1);
        threefry2x32(k2a, k2b, 0u, i1 + 1, o0, o1); float g2 = bits_to_gumbel(o0 ^ o1);
        s_ab[j] = (x + g1 - g2) > 0.0f ? 1.0f : 0.0f;
      }
      __syncthreads();
      const float fg = s_fio[0], ig = s_fio[1], og = s_fio[2];
      const float alpha = s_ab[0], beta = s_ab[1];
      const int c0 = tid * 2;
      {
        float r0 = 0.0f, r1 = 0.0f;
#pragma unroll 4
        for (int k = 0; k < AC; ++k) {
          float rk = sm.ls.rs[k];
          float2 w2 = *(const float2*)&Wr2c[(size_t)k * HD + c0];
          r0 = fmaf(rk, w2.x, r0); r1 = fmaf(rk, w2.y, r1);
        }
        float2 hc2 = cohl2(&hcat[(size_t)b * WC + c0]);
        float2 ic2 = *(const float2*)&icrow[c0];
        float a0 = beta * hc2.x + ic2.x + alpha * r0;
        float a1 = beta * hc2.y + ic2.y + alpha * r1;
        float cn0 = fg * ccL[c0] + ig * tanhf(a0);
        float cn1 = fg * ccL[c0 + 1] + ig * tanhf(a1);
        float hn0 = og * tanhf(cn0), hn1 = og * tanhf(cn1);
        ccL[c0] = cn0; ccL[c0 + 1] = cn1;
        sm.ls.hls[c0] = hn0; sm.ls.hls[c0 + 1] = hn1;
        *(float2*)&out[((size_t)t * BB + b) * HD + c0] = make_float2(hn0, hn1);
        if (t + 1 < LL) cohs2(&hbuf[(size_t)b * HD + c0], make_float2(hn0, hn1));
      }
      __syncthreads();
      if (t + 1 < LL) {
        {  // val = h @ Wh2m (4-way split-K), all private
          int c = tid & 127, q = tid >> 7;
          const float* wp = Wh2m + c;
          float acc = 0.0f;
          int kb = q * 256;
#pragma unroll 4
          for (int k = kb; k < kb + 256; ++k) acc = fmaf(sm.ls.hls[k], wp[(size_t)k * CCd], acc);
          sm.ls.vhalf[tid] = acc;
        }
        __syncthreads();
        if (tid < CCd) {
          float val = sm.ls.vhalf[tid] + sm.ls.vhalf[tid + 128] + sm.ls.vhalf[tid + 256] + sm.ls.vhalf[tid + 384];
          sm.ls.vs[tid] = val;
          valHist[((size_t)b * LL + t) * CCd + tid] = val;
        }
        __syncthreads();
        {  // valW = val @ Wm2w[A:,:] (2-way split)
          int m = tid & 255, h2 = tid >> 8;
          float acc = 0.0f;
          int cb = h2 * 64;
#pragma unroll 4
          for (int cix = cb; cix < cb + 64; ++cix)
            acc = fmaf(sm.ls.vs[cix], Wm2w[(size_t)(AA + cix) * AC + m], acc);
          sm.ls.zn[tid] = acc;
        }
        __syncthreads();
        if (tid < AC) valWHist[((size_t)b * LL + t) * AC + tid] = sm.ls.zn[tid] + sm.ls.zn[tid + 256];
        __syncthreads();
        {  // u2w(t+1) = layernorm(w_sumL) @ Wu2w  (w_sumL updated above)
          float v = w_sumL[tid];
          float ssum = v;
          for (int off = 32; off; off >>= 1) ssum += __shfl_down(ssum, off, 64);
          if (lane == 0) redv[wv] = ssum;
          __syncthreads();
          float mu = (redv[0] + redv[1] + redv[2] + redv[3] + redv[4] + redv[5] + redv[6] + redv[7]) / (float)NS;
          __syncthreads();
          float d = (v - mu) * (v - mu);
          for (int off = 32; off; off >>= 1) d += __shfl_down(d, off, 64);
          if (lane == 0) redv[wv] = d;
          __syncthreads();
          float var = (redv[0] + redv[1] + redv[2] + redv[3] + redv[4] + redv[5] + redv[6] + redv[7]) / (float)NS;
          float rsq = rsqrtf(var + 1e-5f);
          sm.ls.zn[tid] = (v - mu) * rsq;
          __syncthreads();
          {
            int m = tid & 255, h2 = tid >> 8;
            float acc = 0.0f;
            int kb2 = h2 * 256;
#pragma unroll 4
            for (int k = kb2; k < kb2 + 256; ++k) acc = fmaf(sm.ls.zn[k], Wu2w[(size_t)k * AC + m], acc);
            sm.ls.vhalf[tid] = acc;
          }
          __syncthreads();
          if (tid < AC) u2wL[tid] = sm.ls.vhalf[tid] + sm.ls.vhalf[tid + 256];
        }
      }
    }
    if (t + 1 < LL) gbar(bar_cnt, bar_flag, epoch);
  }
}

// ------------------------------ host ---------------------------------------
extern "C" void kernel_launch(void* const* d_in, const int* in_sizes, int n_in,
                              void* d_out, int out_size, void* d_ws, size_t ws_size,
                              hipStream_t stream) {
  const float* inp      = (const float*)d_in[0];
  const float* hid      = (const float*)d_in[1];
  const float* mem_bias = (const float*)d_in[2];
  const float* W_h2w    = (const float*)d_in[3];
  const float* W_i2w    = (const float*)d_in[4];
  const float* W_m2w    = (const float*)d_in[5];
  const float* W_u2w    = (const float*)d_in[6];
  const float* W_h2g    = (const float*)d_in[7];
  const float* W_i2g    = (const float*)d_in[8];
  const float* W_r2g    = (const float*)d_in[9];
  const float* W_h2ab   = (const float*)d_in[10];
  const float* W_i2ab   = (const float*)d_in[11];
  const float* W_r2ab   = (const float*)d_in[12];
  const float* W_h2c    = (const float*)d_in[13];
  const float* W_i2c    = (const float*)d_in[14];
  const float* W_r2c    = (const float*)d_in[15];
  const float* atten    = (const float*)d_in[16];
  const float* W_h2tau  = (const float*)d_in[17];
  const float* b_h2tau  = (const float*)d_in[18];
  const float* W_h2m    = (const float*)d_in[19];
  float* out = (float*)d_out;

  char* base = (char*)d_ws;
  size_t off = 0;
  auto alloc = [&](size_t elems) -> void* {
    void* p = (void*)(base + off);
    off += ((elems * 4 + 255) / 256) * 256;
    return p;
  };
  float* icat     = (float*)alloc((size_t)LL * BB * WC);
  float* Wicat    = (float*)alloc((size_t)ID * WC);
  float* Wcat     = (float*)alloc((size_t)HD * WC);
  float* addrW    = (float*)alloc((size_t)NS * AC);
  float* addrWT   = (float*)alloc((size_t)NS * AC);
  float* hbuf     = (float*)alloc((size_t)BB * HD);
  float* hcat     = (float*)alloc((size_t)BB * WC);
  float* valHist  = (float*)alloc((size_t)BB * LL * CCd);
  float* valWHist = (float*)alloc((size_t)BB * LL * AC);
  int*   writePos = (int*)alloc((size_t)BB * LL);
  int*   lastWriter = (int*)alloc((size_t)BB * NS);
  unsigned int* bar = (unsigned int*)alloc(512);   // [0]=counter, [256]=flag

  hipLaunchKernelGGL(pack_wcat, dim3((HD * WC + 255) / 256), dim3(256), 0, stream,
                     W_h2c, W_h2w, W_h2g, W_h2ab, W_h2tau, Wcat);
  hipLaunchKernelGGL(pack_wicat, dim3((ID * WC + 255) / 256), dim3(256), 0, stream,
                     W_i2c, W_i2w, W_i2g, W_i2ab, Wicat);
  hipLaunchKernelGGL(addrw_kernel, dim3((NS * AC + 255) / 256), dim3(256), 0, stream,
                     mem_bias, W_m2w, addrW, addrWT);
  hipLaunchKernelGGL(init_kernel, dim3((BB * HD + 255) / 256), dim3(256), 0, stream,
                     hid, hbuf, bar);
  hipLaunchKernelGGL(gemm_big, dim3((LL * BB) / 128, WC / 64), dim3(256), 0, stream,
                     inp, Wicat, icat);
  hipLaunchKernelGGL(persist_kernel, dim3(NBLK), dim3(512), 0, stream,
                     icat, Wcat, addrW, addrWT, atten, mem_bias,
                     W_r2g, W_r2ab, W_r2c, W_h2m, W_m2w, W_u2w, b_h2tau,
                     hbuf, hcat, valHist, valWHist, lastWriter, writePos,
                     bar, bar + 256, out);
}